// Round 5
// baseline (39333.157 us; speedup 1.0000x reference)
//
#include <hip/hip_runtime.h>
#include <hip/hip_fp16.h>

typedef _Float16 f16;
typedef _Float16 f16x2 __attribute__((ext_vector_type(2)));
typedef _Float16 f16x8 __attribute__((ext_vector_type(8)));
typedef float f32x4 __attribute__((ext_vector_type(4)));
typedef unsigned int u32;

#define BATCH 32
#define SEQT  2048
#define DIN   256
#define HU    256
#define G4    1024          // 4*H
#define MROWS (BATCH*SEQT)  // 65536

// ---- workspace layout (bytes) ----
#define WS_XW 0
#define WS_XH 134217728UL
#define WS_WT 167772160UL
#define WS_UP 168296448UL
#define WS_NEED 168820736UL

// ---------------- prep kernels ----------------
__global__ void pack_u(const float* __restrict__ U, u32* __restrict__ upk) {
    int idx = blockIdx.x * 256 + threadIdx.x;      // 128*1024
    int p = idx >> 10, j = idx & 1023;
    f16x2 h;
    h.x = (f16)U[(2 * p) * G4 + j];
    h.y = (f16)U[(2 * p + 1) * G4 + j];
    upk[p * G4 + j] = __builtin_bit_cast(u32, h);
}

__global__ void conv_x(const float* __restrict__ x, f16* __restrict__ xh) {
    int idx = blockIdx.x * 256 + threadIdx.x;      // 65536*32
    int row = idx >> 5, c = idx & 31;
    const float4* src = (const float4*)(x + row * 256 + c * 8);
    float4 v0 = src[0], v1 = src[1];
    f16x8 o;
    o[0] = (f16)v0.x; o[1] = (f16)v0.y; o[2] = (f16)v0.z; o[3] = (f16)v0.w;
    o[4] = (f16)v1.x; o[5] = (f16)v1.y; o[6] = (f16)v1.z; o[7] = (f16)v1.w;
    *(f16x8*)(xh + row * 256 + c * 8) = o;
}

__global__ void conv_w(const float* __restrict__ W, f16* __restrict__ wt) {
    int idx = blockIdx.x * 256 + threadIdx.x;      // 1024*32
    int j = idx >> 5, c = idx & 31;
    f16x8 o;
#pragma unroll
    for (int i = 0; i < 8; ++i) o[i] = (f16)W[(c * 8 + i) * G4 + j];
    *(f16x8*)(wt + j * 256 + c * 8) = o;
}

// ---------------- xW GEMM: [65536,256]x[256,1024] fp16 MFMA ----------------
__launch_bounds__(256)
__global__ void gemm_xw(const f16* __restrict__ xh, const f16* __restrict__ wt,
                        const float* __restrict__ bias, f16* __restrict__ xw) {
    __shared__ __align__(16) f16 As[128 * 256];   // 64 KB, swizzled chunks
    __shared__ __align__(16) f16 Bs[128 * 256];   // 64 KB
    int mt = blockIdx.x, nt = blockIdx.y;
    int t = threadIdx.x, lane = t & 63, w = t >> 6;

    const uint4* Ag = (const uint4*)(xh + (size_t)mt * 128 * 256);
    const uint4* Bg = (const uint4*)(wt + (size_t)nt * 128 * 256);
#pragma unroll
    for (int i = 0; i < 16; ++i) {
        int o16 = t + i * 256;            // 16B chunk id 0..4095
        int row = o16 >> 5, c = o16 & 31;
        uint4 va = Ag[o16];
        uint4 vb = Bg[o16];
        int sw = c ^ (row & 7);
        *(uint4*)((char*)As + row * 512 + sw * 16) = va;
        *(uint4*)((char*)Bs + row * 512 + sw * 16) = vb;
    }
    __syncthreads();

    int wr = w >> 1, wc = w & 1;
    f32x4 acc[4][4];
#pragma unroll
    for (int mi = 0; mi < 4; ++mi)
#pragma unroll
        for (int ni = 0; ni < 4; ++ni) acc[mi][ni] = (f32x4){0.f, 0.f, 0.f, 0.f};

    int rA = lane & 15;
    int kg = lane >> 4;    // 0..3 -> k-offset group of 8
#pragma unroll
    for (int ks = 0; ks < 8; ++ks) {
        f16x8 af[4], bf[4];
#pragma unroll
        for (int mi = 0; mi < 4; ++mi) {
            int row = wr * 64 + mi * 16 + rA;
            int c = ks * 4 + kg;
            af[mi] = *(const f16x8*)((const char*)As + row * 512 + ((c ^ (row & 7)) * 16));
        }
#pragma unroll
        for (int ni = 0; ni < 4; ++ni) {
            int row = wc * 64 + ni * 16 + rA;
            int c = ks * 4 + kg;
            bf[ni] = *(const f16x8*)((const char*)Bs + row * 512 + ((c ^ (row & 7)) * 16));
        }
#pragma unroll
        for (int mi = 0; mi < 4; ++mi)
#pragma unroll
            for (int ni = 0; ni < 4; ++ni)
                acc[mi][ni] = __builtin_amdgcn_mfma_f32_16x16x32_f16(af[mi], bf[ni], acc[mi][ni], 0, 0, 0);
    }

    // epilogue: C/D layout col=lane&15, row=(lane>>4)*4+q
    int r4 = (lane >> 4) * 4, cc = lane & 15;
    float bv[4];
#pragma unroll
    for (int ni = 0; ni < 4; ++ni) bv[ni] = bias[nt * 128 + wc * 64 + ni * 16 + cc];
#pragma unroll
    for (int mi = 0; mi < 4; ++mi)
#pragma unroll
        for (int ni = 0; ni < 4; ++ni)
#pragma unroll
            for (int q = 0; q < 4; ++q) {
                int grow = mt * 128 + wr * 64 + mi * 16 + r4 + q;
                int gcol = nt * 128 + wc * 64 + ni * 16 + cc;
                xw[(size_t)grow * 1024 + gcol] = (f16)(acc[mi][ni][q] + bv[ni]);
            }
}

// ---------------- recurrence ----------------
__device__ __forceinline__ float fdot2u(u32 u, u32 h, float acc) {
    return __builtin_amdgcn_fdot2(__builtin_bit_cast(f16x2, u),
                                  __builtin_bit_cast(f16x2, h), acc, false);
}
__device__ __forceinline__ float sigm(float x) {
    return 1.0f / (1.0f + __expf(-x));
}
__device__ __forceinline__ float tanh_f(float x) {
    x = fminf(fmaxf(x, -15.0f), 15.0f);
    float e = __expf(2.0f * x);
    return (e - 1.0f) / (e + 1.0f);
}

// one WG per batch; 512 threads; thread t owns gate-columns t and t+512.
//
// R1-R4 post-mortem: VGPR_Count pinned at 128 across every attribute
// combination, yet the U working set needs 184 dwords/thread. Conclusion:
// the compiler REMATERIALIZES the read-only upk loads inside the step loop
// (legal for __restrict__ loads, cheaper than spilling in its model) ->
// ~184 L2-latency global loads per thread per step -> 8.5us/step latency
// chain. Fix: pin U k-pairs 0..91 in AGPRs via inline asm. An "a"-
// constrained asm result is opaque (cannot be rematerialized) and lives in
// the accumulator half of the gfx950 unified register file. 184 AGPR +
// ~45 arch VGPR fits the 256/wave budget at 2 waves/SIMD (LDS already
// caps occupancy at 1 block/CU). Pairs 92..127 stay in LDS (stride-36,
// measured conflict-free).

#define ASTORE(av, v) asm volatile("v_accvgpr_write_b32 %0, %1" : "=a"(av) : "v"(v))
#define ALOAD(v, av)  asm volatile("v_accvgpr_read_b32 %0, %1"  : "=v"(v) : "a"(av))

#define DECLA(c) u32 a0x_##c, a0y_##c, a0z_##c, a0w_##c, \
                     a1x_##c, a1y_##c, a1z_##c, a1w_##c;

#define LOADA(c) do {                                   \
    u32 q;                                              \
    q = upk[(4*(c)+0)*1024 + t];        ASTORE(a0x_##c, q); \
    q = upk[(4*(c)+1)*1024 + t];        ASTORE(a0y_##c, q); \
    q = upk[(4*(c)+2)*1024 + t];        ASTORE(a0z_##c, q); \
    q = upk[(4*(c)+3)*1024 + t];        ASTORE(a0w_##c, q); \
    q = upk[(4*(c)+0)*1024 + t + 512];  ASTORE(a1x_##c, q); \
    q = upk[(4*(c)+1)*1024 + t + 512];  ASTORE(a1y_##c, q); \
    q = upk[(4*(c)+2)*1024 + t + 512];  ASTORE(a1z_##c, q); \
    q = upk[(4*(c)+3)*1024 + t + 512];  ASTORE(a1w_##c, q); \
} while (0)

#define CHRA(c) do {                                    \
    uint4 hv = *(const uint4*)&hpair[4*(c)];            \
    u32 w0, w1, w2, w3;                                 \
    ALOAD(w0, a0x_##c); ALOAD(w1, a0y_##c);             \
    ALOAD(w2, a0z_##c); ALOAD(w3, a0w_##c);             \
    a0  = fdot2u(w0, hv.x, a0);                         \
    a0b = fdot2u(w1, hv.y, a0b);                        \
    a0  = fdot2u(w2, hv.z, a0);                         \
    a0b = fdot2u(w3, hv.w, a0b);                        \
    ALOAD(w0, a1x_##c); ALOAD(w1, a1y_##c);             \
    ALOAD(w2, a1z_##c); ALOAD(w3, a1w_##c);             \
    a1  = fdot2u(w0, hv.x, a1);                         \
    a1b = fdot2u(w1, hv.y, a1b);                        \
    a1  = fdot2u(w2, hv.z, a1);                         \
    a1b = fdot2u(w3, hv.w, a1b);                        \
} while (0)

__global__
__attribute__((amdgpu_flat_work_group_size(512, 512), amdgpu_waves_per_eu(2, 2)))
void lstm_rec(const u32* __restrict__ upk, const f16* __restrict__ xw,
              float* __restrict__ out) {
    __shared__ __align__(16) u32 ulds[1024 * 36];  // 144 KB: pairs 92..127, col stride 36 dwords
    __shared__ __align__(16) u32 hpair[128];       // 256 h as f16 pairs
    __shared__ float2 fobuf[256];                  // sigmoid(f), sigmoid(o) per unit

    int b = blockIdx.x, t = threadIdx.x;

    DECLA(0)  DECLA(1)  DECLA(2)  DECLA(3)  DECLA(4)  DECLA(5)
    DECLA(6)  DECLA(7)  DECLA(8)  DECLA(9)  DECLA(10) DECLA(11)
    DECLA(12) DECLA(13) DECLA(14) DECLA(15) DECLA(16) DECLA(17)
    DECLA(18) DECLA(19) DECLA(20) DECLA(21) DECLA(22)

    LOADA(0);  LOADA(1);  LOADA(2);  LOADA(3);  LOADA(4);  LOADA(5);
    LOADA(6);  LOADA(7);  LOADA(8);  LOADA(9);  LOADA(10); LOADA(11);
    LOADA(12); LOADA(13); LOADA(14); LOADA(15); LOADA(16); LOADA(17);
    LOADA(18); LOADA(19); LOADA(20); LOADA(21); LOADA(22);

#pragma unroll
    for (int i = 0; i < 36; ++i) {
        ulds[t * 36 + i]         = upk[(92 + i) * 1024 + t];
        ulds[(t + 512) * 36 + i] = upk[(92 + i) * 1024 + t + 512];
    }
    if (t < 128) hpair[t] = 0u;

    float c_state = 0.0f;
    const f16* xp = xw + (size_t)b * SEQT * G4;      // current step's row
    float* op = out + (size_t)b * SEQT * HU;
    f16 xa = xp[t];
    f16 xb = xp[t + 512];
    __syncthreads();

    for (int st = 0; st < SEQT; ++st) {
        float a0 = (float)xa, a1 = (float)xb;
        float a0b = 0.f, a1b = 0.f;
        if (st < SEQT - 1) {   // prefetch next step's xw
            xa = xp[G4 + t];
            xb = xp[G4 + t + 512];
        }
        xp += G4;

        // k-pairs 0..91: U from AGPRs, h broadcast from LDS
        CHRA(0);  CHRA(1);  CHRA(2);  CHRA(3);  CHRA(4);  CHRA(5);
        CHRA(6);  CHRA(7);  CHRA(8);  CHRA(9);  CHRA(10); CHRA(11);
        CHRA(12); CHRA(13); CHRA(14); CHRA(15); CHRA(16); CHRA(17);
        CHRA(18); CHRA(19); CHRA(20); CHRA(21); CHRA(22);

        // k-pairs 92..127: U from LDS
#pragma unroll
        for (int ch = 0; ch < 9; ++ch) {
            uint4 hv = *(const uint4*)&hpair[92 + ch * 4];
            uint4 u0 = *(const uint4*)&ulds[t * 36 + ch * 4];
            uint4 u1 = *(const uint4*)&ulds[(t + 512) * 36 + ch * 4];
            a0  = fdot2u(u0.x, hv.x, a0);
            a0b = fdot2u(u0.y, hv.y, a0b);
            a0  = fdot2u(u0.z, hv.z, a0);
            a0b = fdot2u(u0.w, hv.w, a0b);
            a1  = fdot2u(u1.x, hv.x, a1);
            a1b = fdot2u(u1.y, hv.y, a1b);
            a1  = fdot2u(u1.z, hv.z, a1);
            a1b = fdot2u(u1.w, hv.w, a1b);
        }
        a0 += a0b;
        a1 += a1b;

        // t<256: a0=i, a1=g ; t>=256: a0=f, a1=o
        float act0 = sigm(a0);
        float act1 = (t < 256) ? tanh_f(a1) : sigm(a1);
        if (t >= 256) fobuf[t - 256] = make_float2(act0, act1);
        __syncthreads();
        if (t < 256) {
            float2 fo = fobuf[t];
            c_state = fo.x * c_state + act0 * act1;
            float h = fo.y * tanh_f(c_state);
            op[t] = h;
            ((f16*)hpair)[t] = (f16)h;
        }
        op += HU;
        __syncthreads();
    }
}

extern "C" void kernel_launch(void* const* d_in, const int* in_sizes, int n_in,
                              void* d_out, int out_size, void* d_ws, size_t ws_size,
                              hipStream_t stream) {
    const float* x    = (const float*)d_in[0];
    const float* W    = (const float*)d_in[1];
    const float* U    = (const float*)d_in[2];
    const float* bias = (const float*)d_in[3];
    float* out = (float*)d_out;

    if (ws_size < WS_NEED) return;  // fail loudly rather than corrupt
    char* ws = (char*)d_ws;
    f16* xw  = (f16*)(ws + WS_XW);
    f16* xh  = (f16*)(ws + WS_XH);
    f16* wt  = (f16*)(ws + WS_WT);
    u32* upk = (u32*)(ws + WS_UP);

    pack_u<<<512, 256, 0, stream>>>(U, upk);
    conv_x<<<8192, 256, 0, stream>>>(x, xh);
    conv_w<<<128, 256, 0, stream>>>(W, wt);
    gemm_xw<<<dim3(512, 8), 256, 0, stream>>>(xh, wt, bias, xw);
    lstm_rec<<<32, 512, 0, stream>>>(upk, xw, out);
}

// Round 6
// 4134.718 us; speedup vs baseline: 9.5129x; 9.5129x over previous
//
#include <hip/hip_runtime.h>
#include <hip/hip_fp16.h>

typedef _Float16 f16;
typedef _Float16 f16x2 __attribute__((ext_vector_type(2)));
typedef _Float16 f16x8 __attribute__((ext_vector_type(8)));
typedef float f32x4 __attribute__((ext_vector_type(4)));
typedef unsigned int u32;

#define BATCH 32
#define SEQT  2048
#define DIN   256
#define HU    256
#define G4    1024          // 4*H
#define MROWS (BATCH*SEQT)  // 65536

// ---- workspace layout (bytes) ----
#define WS_XW 0
#define WS_XH 134217728UL
#define WS_WT 167772160UL
#define WS_UP 168296448UL
#define WS_NEED 168820736UL

// ---------------- prep kernels ----------------
__global__ void pack_u(const float* __restrict__ U, u32* __restrict__ upk) {
    int idx = blockIdx.x * 256 + threadIdx.x;      // 128*1024
    int p = idx >> 10, j = idx & 1023;
    f16x2 h;
    h.x = (f16)U[(2 * p) * G4 + j];
    h.y = (f16)U[(2 * p + 1) * G4 + j];
    upk[p * G4 + j] = __builtin_bit_cast(u32, h);
}

__global__ void conv_x(const float* __restrict__ x, f16* __restrict__ xh) {
    int idx = blockIdx.x * 256 + threadIdx.x;      // 65536*32
    int row = idx >> 5, c = idx & 31;
    const float4* src = (const float4*)(x + row * 256 + c * 8);
    float4 v0 = src[0], v1 = src[1];
    f16x8 o;
    o[0] = (f16)v0.x; o[1] = (f16)v0.y; o[2] = (f16)v0.z; o[3] = (f16)v0.w;
    o[4] = (f16)v1.x; o[5] = (f16)v1.y; o[6] = (f16)v1.z; o[7] = (f16)v1.w;
    *(f16x8*)(xh + row * 256 + c * 8) = o;
}

__global__ void conv_w(const float* __restrict__ W, f16* __restrict__ wt) {
    int idx = blockIdx.x * 256 + threadIdx.x;      // 1024*32
    int j = idx >> 5, c = idx & 31;
    f16x8 o;
#pragma unroll
    for (int i = 0; i < 8; ++i) o[i] = (f16)W[(c * 8 + i) * G4 + j];
    *(f16x8*)(wt + j * 256 + c * 8) = o;
}

// ---------------- xW GEMM: [65536,256]x[256,1024] fp16 MFMA ----------------
__launch_bounds__(256)
__global__ void gemm_xw(const f16* __restrict__ xh, const f16* __restrict__ wt,
                        const float* __restrict__ bias, f16* __restrict__ xw) {
    __shared__ __align__(16) f16 As[128 * 256];   // 64 KB, swizzled chunks
    __shared__ __align__(16) f16 Bs[128 * 256];   // 64 KB
    int mt = blockIdx.x, nt = blockIdx.y;
    int t = threadIdx.x, lane = t & 63, w = t >> 6;

    const uint4* Ag = (const uint4*)(xh + (size_t)mt * 128 * 256);
    const uint4* Bg = (const uint4*)(wt + (size_t)nt * 128 * 256);
#pragma unroll
    for (int i = 0; i < 16; ++i) {
        int o16 = t + i * 256;            // 16B chunk id 0..4095
        int row = o16 >> 5, c = o16 & 31;
        uint4 va = Ag[o16];
        uint4 vb = Bg[o16];
        int sw = c ^ (row & 7);
        *(uint4*)((char*)As + row * 512 + sw * 16) = va;
        *(uint4*)((char*)Bs + row * 512 + sw * 16) = vb;
    }
    __syncthreads();

    int wr = w >> 1, wc = w & 1;
    f32x4 acc[4][4];
#pragma unroll
    for (int mi = 0; mi < 4; ++mi)
#pragma unroll
        for (int ni = 0; ni < 4; ++ni) acc[mi][ni] = (f32x4){0.f, 0.f, 0.f, 0.f};

    int rA = lane & 15;
    int kg = lane >> 4;    // 0..3 -> k-offset group of 8
#pragma unroll
    for (int ks = 0; ks < 8; ++ks) {
        f16x8 af[4], bf[4];
#pragma unroll
        for (int mi = 0; mi < 4; ++mi) {
            int row = wr * 64 + mi * 16 + rA;
            int c = ks * 4 + kg;
            af[mi] = *(const f16x8*)((const char*)As + row * 512 + ((c ^ (row & 7)) * 16));
        }
#pragma unroll
        for (int ni = 0; ni < 4; ++ni) {
            int row = wc * 64 + ni * 16 + rA;
            int c = ks * 4 + kg;
            bf[ni] = *(const f16x8*)((const char*)Bs + row * 512 + ((c ^ (row & 7)) * 16));
        }
#pragma unroll
        for (int mi = 0; mi < 4; ++mi)
#pragma unroll
            for (int ni = 0; ni < 4; ++ni)
                acc[mi][ni] = __builtin_amdgcn_mfma_f32_16x16x32_f16(af[mi], bf[ni], acc[mi][ni], 0, 0, 0);
    }

    // epilogue: C/D layout col=lane&15, row=(lane>>4)*4+q
    int r4 = (lane >> 4) * 4, cc = lane & 15;
    float bv[4];
#pragma unroll
    for (int ni = 0; ni < 4; ++ni) bv[ni] = bias[nt * 128 + wc * 64 + ni * 16 + cc];
#pragma unroll
    for (int mi = 0; mi < 4; ++mi)
#pragma unroll
        for (int ni = 0; ni < 4; ++ni)
#pragma unroll
            for (int q = 0; q < 4; ++q) {
                int grow = mt * 128 + wr * 64 + mi * 16 + r4 + q;
                int gcol = nt * 128 + wc * 64 + ni * 16 + cc;
                xw[(size_t)grow * 1024 + gcol] = (f16)(acc[mi][ni][q] + bv[ni]);
            }
}

// ---------------- recurrence ----------------
__device__ __forceinline__ float fdot2u(u32 u, u32 h, float acc) {
    return __builtin_amdgcn_fdot2(__builtin_bit_cast(f16x2, u),
                                  __builtin_bit_cast(f16x2, h), acc, false);
}
__device__ __forceinline__ float sigm(float x) {
    return 1.0f / (1.0f + __expf(-x));
}
__device__ __forceinline__ float tanh_f(float x) {
    x = fminf(fmaxf(x, -15.0f), 15.0f);
    float e = __expf(2.0f * x);
    return (e - 1.0f) / (e + 1.0f);
}

// ---- R6 redesign: fit the 128-VGPR budget instead of fighting it ----
// 1024 threads/WG, one WG per batch. Thread t owns gate-column t
// (gate = t>>8 in [i,f,g,o], unit = t&255; branch is wave-uniform).
// Per thread: 92 U-pairs (k 0..183) in 23 NAMED uint4 registers
// (~117 VGPRs total demand, fits the 128 budget the backend has enforced
// in R1-R5), 36 U-pairs (k 184..255) in LDS stride-36 (measured
// conflict-free, SQ_LDS_BANK_CONFLICT=0).
// Occupancy: 1 WG/CU (152 KB LDS), 16 waves = 4 waves/SIMD.
// Gate exchange per step via 4 KB LDS gbuf; threads 0..255 keep c_state
// and produce h.

#define DECLC(c) uint4 uc_##c;
#define LOADC(c) do {                              \
    uc_##c.x = upk[(4*(c)+0)*1024 + t];            \
    uc_##c.y = upk[(4*(c)+1)*1024 + t];            \
    uc_##c.z = upk[(4*(c)+2)*1024 + t];            \
    uc_##c.w = upk[(4*(c)+3)*1024 + t];            \
} while (0)
#define CHR(c) do {                                \
    uint4 hv = *(const uint4*)&hpair[4*(c)];       \
    a0 = fdot2u(uc_##c.x, hv.x, a0);               \
    a1 = fdot2u(uc_##c.y, hv.y, a1);               \
    a2 = fdot2u(uc_##c.z, hv.z, a2);               \
    a3 = fdot2u(uc_##c.w, hv.w, a3);               \
} while (0)

__launch_bounds__(1024)
__global__ void lstm_rec(const u32* __restrict__ upk, const f16* __restrict__ xw,
                         float* __restrict__ out) {
    __shared__ __align__(16) u32 ulds[1024 * 36];  // 144 KB: U pairs 92..127, [col][pair], stride 36
    __shared__ __align__(16) u32 hpair[128];       // 256 h as f16 pairs
    __shared__ __align__(16) float gbuf[1024];     // per-column activated gate values

    int b = blockIdx.x, t = threadIdx.x;

    DECLC(0)  DECLC(1)  DECLC(2)  DECLC(3)  DECLC(4)  DECLC(5)
    DECLC(6)  DECLC(7)  DECLC(8)  DECLC(9)  DECLC(10) DECLC(11)
    DECLC(12) DECLC(13) DECLC(14) DECLC(15) DECLC(16) DECLC(17)
    DECLC(18) DECLC(19) DECLC(20) DECLC(21) DECLC(22)

    LOADC(0);  LOADC(1);  LOADC(2);  LOADC(3);  LOADC(4);  LOADC(5);
    LOADC(6);  LOADC(7);  LOADC(8);  LOADC(9);  LOADC(10); LOADC(11);
    LOADC(12); LOADC(13); LOADC(14); LOADC(15); LOADC(16); LOADC(17);
    LOADC(18); LOADC(19); LOADC(20); LOADC(21); LOADC(22);

#pragma unroll
    for (int i = 0; i < 36; ++i)
        ulds[t * 36 + i] = upk[(92 + i) * 1024 + t];
    if (t < 128) hpair[t] = 0u;

    float c_state = 0.0f;
    const f16* xp = xw + (size_t)b * SEQT * G4;
    float* op = out + (size_t)b * SEQT * HU;
    f16 xa = xp[t];
    __syncthreads();

    for (int st = 0; st < SEQT; ++st) {
        float a0 = (float)xa, a1 = 0.f, a2 = 0.f, a3 = 0.f;
        if (st < SEQT - 1) xa = xp[G4 + t];   // prefetch next step
        xp += G4;

        // k-pairs 0..91: U from named registers, h broadcast from LDS
        CHR(0);  CHR(1);  CHR(2);  CHR(3);  CHR(4);  CHR(5);
        CHR(6);  CHR(7);  CHR(8);  CHR(9);  CHR(10); CHR(11);
        CHR(12); CHR(13); CHR(14); CHR(15); CHR(16); CHR(17);
        CHR(18); CHR(19); CHR(20); CHR(21); CHR(22);

        // k-pairs 92..127: U from LDS
#pragma unroll
        for (int ch = 0; ch < 9; ++ch) {
            uint4 hv = *(const uint4*)&hpair[92 + ch * 4];
            uint4 u4 = *(const uint4*)&ulds[t * 36 + ch * 4];
            a0 = fdot2u(u4.x, hv.x, a0);
            a1 = fdot2u(u4.y, hv.y, a1);
            a2 = fdot2u(u4.z, hv.z, a2);
            a3 = fdot2u(u4.w, hv.w, a3);
        }
        float a = (a0 + a1) + (a2 + a3);

        // activation: gate = t>>8 (wave-uniform). g-gate (2) is tanh.
        float act = ((t >> 8) == 2) ? tanh_f(a) : sigm(a);
        gbuf[t] = act;
        __syncthreads();

        if (t < 256) {
            float gi = gbuf[t];
            float gf = gbuf[256 + t];
            float gg = gbuf[512 + t];
            float go = gbuf[768 + t];
            c_state = gf * c_state + gi * gg;
            float h = go * tanh_f(c_state);
            op[t] = h;
            ((f16*)hpair)[t] = (f16)h;
        }
        op += HU;
        __syncthreads();
    }
}

extern "C" void kernel_launch(void* const* d_in, const int* in_sizes, int n_in,
                              void* d_out, int out_size, void* d_ws, size_t ws_size,
                              hipStream_t stream) {
    const float* x    = (const float*)d_in[0];
    const float* W    = (const float*)d_in[1];
    const float* U    = (const float*)d_in[2];
    const float* bias = (const float*)d_in[3];
    float* out = (float*)d_out;

    if (ws_size < WS_NEED) return;  // fail loudly rather than corrupt
    char* ws = (char*)d_ws;
    f16* xw  = (f16*)(ws + WS_XW);
    f16* xh  = (f16*)(ws + WS_XH);
    f16* wt  = (f16*)(ws + WS_WT);
    u32* upk = (u32*)(ws + WS_UP);

    pack_u<<<512, 256, 0, stream>>>(U, upk);
    conv_x<<<8192, 256, 0, stream>>>(x, xh);
    conv_w<<<128, 256, 0, stream>>>(W, wt);
    gemm_xw<<<dim3(512, 8), 256, 0, stream>>>(xh, wt, bias, xw);
    lstm_rec<<<32, 1024, 0, stream>>>(upk, xw, out);
}